// Round 7
// baseline (186.252 us; speedup 1.0000x reference)
//
#include <hip/hip_runtime.h>
#include <stdint.h>

typedef unsigned short u16;
typedef uint32_t u32;
typedef __bf16 bf16x8 __attribute__((ext_vector_type(8)));
typedef float f32x4 __attribute__((ext_vector_type(4)));
typedef uint32_t u32x4 __attribute__((ext_vector_type(4)));

__device__ __forceinline__ u16 f2bf(float f) {
    union { float f; uint32_t u; } c; c.f = f;
    return (u16)((c.u + 0x7fffu + ((c.u >> 16) & 1u)) >> 16);  // RNE
}

__device__ __forceinline__ void g2lds16(const u16* g, u16* l) {
    __builtin_amdgcn_global_load_lds(
        (__attribute__((address_space(1))) void*)(void*)(g),
        (__attribute__((address_space(3))) void*)(l),
        16, 0, 0);
}

template <int N> __device__ __forceinline__ void waitcnt_vm() {
    if constexpr      (N == 8) asm volatile("s_waitcnt vmcnt(8)" ::: "memory");
    else if constexpr (N == 6) asm volatile("s_waitcnt vmcnt(6)" ::: "memory");
    else if constexpr (N == 4) asm volatile("s_waitcnt vmcnt(4)" ::: "memory");
    else if constexpr (N == 3) asm volatile("s_waitcnt vmcnt(3)" ::: "memory");
    else                       asm volatile("s_waitcnt vmcnt(0)" ::: "memory");
}

// ---------- fused f32 -> bf16 convert (x, Wq, Wk, Wv in one launch) ----------

__global__ __launch_bounds__(256)
void cvt_all(const float* __restrict__ x, const float* __restrict__ wq,
             const float* __restrict__ wk, const float* __restrict__ wv,
             u16* __restrict__ xb, u16* __restrict__ wb) {
    const int b = blockIdx.x, tid = threadIdx.x;
    const float* src; u16* dst; int off;
    if (b < 2048) { src = x; dst = xb; off = b * 1024; }
    else {
        int w = (b - 2048) >> 8;
        src = (w == 0) ? wq : (w == 1) ? wk : wv;
        dst = wb + (size_t)w * 1048576;
        off = ((b - 2048) & 255) * 1024;
    }
    #pragma unroll
    for (int k2 = 0; k2 < 4; ++k2) {
        int i = off + k2 * 256 + tid;
        float4 f = reinterpret_cast<const float4*>(src)[i];
        ushort4 u{ f2bf(f.x), f2bf(f.y), f2bf(f.z), f2bf(f.w) };
        reinterpret_cast<ushort4*>(dst)[i] = u;
    }
}

// ---------- 256xBN deep-pipelined B^T GEMM ----------
// C[m][n] = scale * sum_k A[m][k]*B[n][k].  BK=32, 4-slot LDS ring, 8 waves.
// NWC=4: BN=256, waves 2Mx4N (wave tile 128x64), 128KB LDS, L=4 loads/tile.
// NWC=2: BN=128, waves 4Mx2N (wave tile  64x64),  96KB LDS, L=3 loads/tile.
// MODE 0: bf16 row-major via LDS-staged coalesced store (NWC=4; r4-verified).
// MODE 1: f32*scale direct store (r4-verified).
// MODE 3: bf16 transposed store to vT[1024][8192] (NWC=2; r5 code under test).

template <int MODE, int NWC>
__global__ __launch_bounds__(512, 2)
void gemm256(const u16* __restrict__ A, const u16* __restrict__ B,
             void* __restrict__ Cv, u16* __restrict__ vTp,
             int K, int lda, int ldb, int ldc,
             int bshift, size_t strideB, float scale)
{
    constexpr int MACC = (NWC == 4) ? 8 : 4;   // A-frag repeats per wave
    constexpr int PH   = MACC / 2;             // per phase
    constexpr int SLOT = 8192 + 2048 * NWC;    // u16 per ring slot
    constexpr int SBC  = NWC / 2;              // B stage calls per tile
    constexpr int L    = 2 + SBC;              // loads per tile

    __shared__ __align__(16) u16 lds[4 * SLOT];

    const int tid  = threadIdx.x;
    const int wid  = tid >> 6, lane = tid & 63;
    const int wr = wid / NWC, wc = wid % NWC;
    const int row0 = blockIdx.y * 256;
    const int col0 = blockIdx.x * (64 * NWC);
    const u16* Bb = B + (size_t)(row0 >> bshift) * strideB;

    // staging per-thread constants (each call: 512 lanes x 16B = 8KB)
    int s_row[2], s_k[2], s_dst[2];
    #pragma unroll
    for (int c = 0; c < 2; ++c) {
        int p = c * 512 + tid;
        int line = p >> 3, ls = (p & 7) ^ (line & 7);
        s_row[c] = 2 * line + (ls >> 2);
        s_k[c]   = (ls & 3) * 8;
        s_dst[c] = (c * 512 + (tid & ~63)) * 8;
    }

    auto stageA = [&](int T) {
        const int sb = (T & 3) * SLOT, k0 = T * 32;
        #pragma unroll
        for (int c = 0; c < 2; ++c)
            g2lds16(A + (size_t)(row0 + s_row[c]) * lda + k0 + s_k[c],
                    &lds[sb + s_dst[c]]);
    };
    auto stageB = [&](int T) {
        const int sb = (T & 3) * SLOT, k0 = T * 32;
        #pragma unroll
        for (int c = 0; c < SBC; ++c)
            g2lds16(Bb + (size_t)(col0 + s_row[c]) * ldb + k0 + s_k[c],
                    &lds[sb + 8192 + s_dst[c]]);
    };

    const int rl = lane & 15, kq = lane >> 4;
    const int ls2  = ((rl & 1) * 4 + kq) ^ ((rl >> 1) & 7);
    const int aoff = (wr * (MACC * 8) + (rl >> 1)) * 64 + ls2 * 8;
    const int boff = 8192 + (wc * 32 + (rl >> 1)) * 64 + ls2 * 8;

    f32x4 acc[MACC][4] = {};
    bf16x8 afr[PH], bfr[4];

    stageA(0); stageB(0); stageA(1); stageB(1); stageA(2); stageB(2);
    waitcnt_vm<2 * L>();
    __builtin_amdgcn_s_barrier();

    const int NT = K >> 5;
    for (int T = 0; T < NT; ++T) {
        const int sb = (T & 3) * SLOT;

        // ---- phase 1 ----
        #pragma unroll
        for (int m = 0; m < PH; ++m) afr[m] = *(const bf16x8*)&lds[sb + aoff + m * 512];
        #pragma unroll
        for (int n = 0; n < 4; ++n)  bfr[n] = *(const bf16x8*)&lds[sb + boff + n * 512];
        if (T + 3 < NT) stageA(T + 3);
        __builtin_amdgcn_s_barrier();
        asm volatile("s_waitcnt lgkmcnt(0)" ::: "memory");
        __builtin_amdgcn_sched_barrier(0);
        __builtin_amdgcn_s_setprio(1);
        #pragma unroll
        for (int m = 0; m < PH; ++m)
            #pragma unroll
            for (int n = 0; n < 4; ++n)
                acc[m][n] = __builtin_amdgcn_mfma_f32_16x16x32_bf16(afr[m], bfr[n], acc[m][n], 0, 0, 0);
        __builtin_amdgcn_s_setprio(0);
        __builtin_amdgcn_s_barrier();

        // ---- phase 2 ----
        #pragma unroll
        for (int m = 0; m < PH; ++m) afr[m] = *(const bf16x8*)&lds[sb + aoff + (m + PH) * 512];
        if (T + 3 < NT) stageB(T + 3);
        if (T < NT - 3)       waitcnt_vm<2 * L>();
        else if (T == NT - 3) waitcnt_vm<L>();
        else if (T == NT - 2) waitcnt_vm<0>();
        __builtin_amdgcn_s_barrier();
        asm volatile("s_waitcnt lgkmcnt(0)" ::: "memory");
        __builtin_amdgcn_sched_barrier(0);
        __builtin_amdgcn_s_setprio(1);
        #pragma unroll
        for (int m = 0; m < PH; ++m)
            #pragma unroll
            for (int n = 0; n < 4; ++n)
                acc[m + PH][n] = __builtin_amdgcn_mfma_f32_16x16x32_bf16(afr[m], bfr[n], acc[m + PH][n], 0, 0, 0);
        __builtin_amdgcn_s_setprio(0);
        __builtin_amdgcn_s_barrier();
    }

    // ---------- epilogue ----------
    // C/D frag: col = col0 + wc*64 + n*16 + rl ; row = row0 + wr*MACC*16 + m*16 + kq*4 + j
    const int kq4 = kq * 4;

    if constexpr (MODE == 1) {
        float* C = (float*)Cv;
        #pragma unroll
        for (int m = 0; m < MACC; ++m)
            #pragma unroll
            for (int j = 0; j < 4; ++j) {
                size_t r = (size_t)(row0 + wr * (MACC * 16) + m * 16 + kq4 + j) * ldc;
                #pragma unroll
                for (int n = 0; n < 4; ++n)
                    C[r + col0 + wc * 64 + n * 16 + rl] = acc[m][n][j] * scale;
            }
    } else if constexpr (MODE == 0) {
        // bf16: stage per-wave 64x64 f32 tiles in own LDS region, store coalesced
        float* tw = (float*)&lds[(size_t)wid * 8192];   // [64 rows][64 cols] swizzled
        u16* Cq = (u16*)Cv;
        #pragma unroll
        for (int h = 0; h < MACC / 4; ++h) {
            #pragma unroll
            for (int mm = 0; mm < 4; ++mm)
                #pragma unroll
                for (int n = 0; n < 4; ++n)
                    #pragma unroll
                    for (int j = 0; j < 4; ++j) {
                        int rowl = mm * 16 + kq4 + j;
                        int c2 = (rl + n * 16) ^ ((((rowl) >> 2) & 3) << 4);
                        tw[rowl * 64 + c2] = acc[h * 4 + mm][n][j];
                    }
            #pragma unroll
            for (int it = 0; it < 16; ++it) {
                int rowr = it * 4 + kq;
                int c2 = (rl * 4) ^ ((it & 3) << 4);
                f32x4 v4 = *(const f32x4*)&tw[rowr * 64 + c2];
                ushort4 u{ f2bf(v4[0]), f2bf(v4[1]), f2bf(v4[2]), f2bf(v4[3]) };
                *(ushort4*)&Cq[(size_t)(row0 + wr * (MACC * 16) + h * 64 + rowr) * ldc
                               + col0 + wc * 64 + rl * 4] = u;
            }
        }
    } else {
        // MODE 3 (NWC=2): transposed bf16 store, wave tile 64(s) x 64(f) -> vT[f][s]
        u32* tv = (u32*)&lds[(size_t)wid * 4096];       // [64 f][32 s2] swizzled (8KB)
        const int s0  = row0 + wr * 64;
        const int f0v = col0 + wc * 64;
        #pragma unroll
        for (int m = 0; m < 4; ++m)
            #pragma unroll
            for (int n = 0; n < 4; ++n)
                #pragma unroll
                for (int j2 = 0; j2 < 2; ++j2) {
                    int fl = rl + n * 16;
                    int s2 = m * 8 + kq * 2 + j2;
                    u32 pk = (u32)f2bf(acc[m][n][j2 * 2])
                           | ((u32)f2bf(acc[m][n][j2 * 2 + 1]) << 16);
                    tv[fl * 32 + (s2 ^ ((fl & 7) << 2))] = pk;
                }
        #pragma unroll
        for (int it = 0; it < 8; ++it) {
            int fr = it * 8 + (lane >> 3);
            int ck = lane & 7;
            int s2s = (ck * 4) ^ ((fr & 7) << 2);
            u32x4 v4 = *(const u32x4*)&tv[fr * 32 + s2s];
            *(u32x4*)&vTp[(size_t)(f0v + fr) * 8192 + s0 + ck * 8] = v4;
        }
    }
}

// ---------- row softmax (2048 f32 -> 2048 bf16 in-place per row) ----------
// One block per row. Writes bf16 P over the FIRST 4KB of the row's own 8KB
// storage (same row only -> no cross-block hazard). P row stride = 4096 u16.

__global__ __launch_bounds__(256)
void softmax_bf16(float* __restrict__ scores) {
    const size_t row = blockIdx.x;
    float* rp = scores + row * 2048;
    const int tid = threadIdx.x;
    const int lane = tid & 63, wid = tid >> 6;

    float4 a = reinterpret_cast<const float4*>(rp)[tid * 2];
    float4 b = reinterpret_cast<const float4*>(rp)[tid * 2 + 1];
    float v[8] = { a.x, a.y, a.z, a.w, b.x, b.y, b.z, b.w };

    float mx = v[0];
    #pragma unroll
    for (int j = 1; j < 8; ++j) mx = fmaxf(mx, v[j]);
    #pragma unroll
    for (int off = 32; off >= 1; off >>= 1) mx = fmaxf(mx, __shfl_xor(mx, off));

    __shared__ float red_mx[4], red_s[4];
    if (lane == 0) red_mx[wid] = mx;
    __syncthreads();
    mx = fmaxf(fmaxf(red_mx[0], red_mx[1]), fmaxf(red_mx[2], red_mx[3]));

    float s = 0.f;
    #pragma unroll
    for (int j = 0; j < 8; ++j) { v[j] = __expf(v[j] - mx); s += v[j]; }
    #pragma unroll
    for (int off = 32; off >= 1; off >>= 1) s += __shfl_xor(s, off);
    if (lane == 0) red_s[wid] = s;
    __syncthreads();
    s = (red_s[0] + red_s[1]) + (red_s[2] + red_s[3]);
    float inv = 1.0f / s;

    u16* pw = (u16*)rp;
    ushort4 u0{ f2bf(v[0] * inv), f2bf(v[1] * inv), f2bf(v[2] * inv), f2bf(v[3] * inv) };
    ushort4 u1{ f2bf(v[4] * inv), f2bf(v[5] * inv), f2bf(v[6] * inv), f2bf(v[7] * inv) };
    reinterpret_cast<ushort4*>(pw)[tid * 2]     = u0;
    reinterpret_cast<ushort4*>(pw)[tid * 2 + 1] = u1;
}

// ---------- launch ----------

extern "C" void kernel_launch(void* const* d_in, const int* in_sizes, int n_in,
                              void* d_out, int out_size, void* d_ws, size_t ws_size,
                              hipStream_t stream) {
    const float* x  = (const float*)d_in[0];
    const float* Wq = (const float*)d_in[1];
    const float* Wk = (const float*)d_in[2];
    const float* Wv = (const float*)d_in[3];

    // ws (MiB) — r4 plan: [0,64) sc f32 | aliased: [0,16) xb, [16,22) Wqkv
    // (both dead before sc is written) | [64,96) qk bf16 [8192][2048] |
    // [96,112) vT bf16 [1024][8192]
    const size_t MiB = 1024 * 1024;
    if (ws_size < 112 * MiB) return;
    char* base = (char*)d_ws;
    float* sc   = (float*)base;
    u16*  xb    = (u16*)base;
    u16*  Wqkvb = (u16*)(base + 16 * MiB);
    u16*  qkb   = (u16*)(base + 64 * MiB);
    u16*  vT    = (u16*)(base + 96 * MiB);

    cvt_all<<<2816, 256, 0, stream>>>(x, Wq, Wk, Wv, xb, Wqkvb);

    // qk = x @ [Wq;Wk]^T : M=8192, N=2048, K=1024 -> bf16 qkb   (grid = 256)
    gemm256<0, 4><<<dim3(8, 32), 512, 0, stream>>>(xb, Wqkvb, qkb, nullptr,
        1024, 1024, 1024, 2048, 31, 0, 1.0f);

    // v = x @ Wv^T, stored transposed -> vT[f][s_global]        (grid = 256)
    gemm256<3, 2><<<dim3(8, 32), 512, 0, stream>>>(xb, Wqkvb + 2097152, nullptr, vT,
        1024, 1024, 1024, 8192, 31, 0, 1.0f);

    // scores = q @ k^T / 32 : M=8192, N=2048, K=1024 -> f32 sc  (grid = 256)
    gemm256<1, 4><<<dim3(8, 32), 512, 0, stream>>>(qkb, qkb + 1024, sc, nullptr,
        1024, 2048, 2048, 2048, 11, (size_t)2048 * 2048, 0.03125f);

    // softmax rows -> bf16 P in place (P lda = 4096 u16)
    softmax_bf16<<<8192, 256, 0, stream>>>(sc);

    // out = P @ vT^T : M=8192, N=1024(f), K=2048(s) -> f32 d_out (grid = 256)
    gemm256<1, 2><<<dim3(8, 32), 512, 0, stream>>>((const u16*)sc, vT, d_out, nullptr,
        2048, 4096, 8192, 1024, 11, 2048, 1.0f);
}

// Round 8
// 185.944 us; speedup vs baseline: 1.0017x; 1.0017x over previous
//
#include <hip/hip_runtime.h>
#include <stdint.h>

typedef unsigned short u16;
typedef uint32_t u32;
typedef __bf16 bf16x8 __attribute__((ext_vector_type(8)));
typedef float f32x4 __attribute__((ext_vector_type(4)));
typedef uint32_t u32x4 __attribute__((ext_vector_type(4)));

__device__ __forceinline__ u16 f2bf(float f) {
    union { float f; uint32_t u; } c; c.f = f;
    return (u16)((c.u + 0x7fffu + ((c.u >> 16) & 1u)) >> 16);  // RNE
}

__device__ __forceinline__ void g2lds16(const u16* g, u16* l) {
    __builtin_amdgcn_global_load_lds(
        (__attribute__((address_space(1))) void*)(void*)(g),
        (__attribute__((address_space(3))) void*)(l),
        16, 0, 0);
}

template <int N> __device__ __forceinline__ void waitcnt_vm() {
    if constexpr      (N == 8) asm volatile("s_waitcnt vmcnt(8)" ::: "memory");
    else if constexpr (N == 6) asm volatile("s_waitcnt vmcnt(6)" ::: "memory");
    else if constexpr (N == 4) asm volatile("s_waitcnt vmcnt(4)" ::: "memory");
    else if constexpr (N == 3) asm volatile("s_waitcnt vmcnt(3)" ::: "memory");
    else                       asm volatile("s_waitcnt vmcnt(0)" ::: "memory");
}

// ---------- fused f32 -> bf16 convert (x, Wq, Wk, Wv in one launch) ----------

__global__ __launch_bounds__(256)
void cvt_all(const float* __restrict__ x, const float* __restrict__ wq,
             const float* __restrict__ wk, const float* __restrict__ wv,
             u16* __restrict__ xb, u16* __restrict__ wb) {
    const int b = blockIdx.x, tid = threadIdx.x;
    const float* src; u16* dst; int off;
    if (b < 2048) { src = x; dst = xb; off = b * 1024; }
    else {
        int w = (b - 2048) >> 8;
        src = (w == 0) ? wq : (w == 1) ? wk : wv;
        dst = wb + (size_t)w * 1048576;
        off = ((b - 2048) & 255) * 1024;
    }
    #pragma unroll
    for (int k2 = 0; k2 < 4; ++k2) {
        int i = off + k2 * 256 + tid;
        float4 f = reinterpret_cast<const float4*>(src)[i];
        ushort4 u{ f2bf(f.x), f2bf(f.y), f2bf(f.z), f2bf(f.w) };
        reinterpret_cast<ushort4*>(dst)[i] = u;
    }
}

// ---------- 256xBN deep-pipelined B^T GEMM ----------
// C[m][n] = scale * sum_k A[m][k]*B[n][k].  BK=32, 4-slot LDS ring, 8 waves.
// NWC=4: BN=256, waves 2Mx4N (wave tile 128x64), 128KB LDS, L=4 loads/tile.
// NWC=2: BN=128, waves 4Mx2N (wave tile  64x64),  96KB LDS, L=3 loads/tile.
// MODE 0: bf16 row-major via LDS-staged coalesced store (NWC=4; r4-verified).
// MODE 1: f32*scale direct store (r4-verified).
// MODE 3: bf16 transposed store to vT[1024][8192] (NWC=2; r5 code under test).

template <int MODE, int NWC>
__global__ __launch_bounds__(512, 2)
void gemm256(const u16* __restrict__ A, const u16* __restrict__ B,
             void* __restrict__ Cv, u16* __restrict__ vTp,
             int K, int lda, int ldb, int ldc,
             int bshift, size_t strideB, float scale)
{
    constexpr int MACC = (NWC == 4) ? 8 : 4;   // A-frag repeats per wave
    constexpr int PH   = MACC / 2;             // per phase
    constexpr int SLOT = 8192 + 2048 * NWC;    // u16 per ring slot
    constexpr int SBC  = NWC / 2;              // B stage calls per tile
    constexpr int L    = 2 + SBC;              // loads per tile

    __shared__ __align__(16) u16 lds[4 * SLOT];

    const int tid  = threadIdx.x;
    const int wid  = tid >> 6, lane = tid & 63;
    const int wr = wid / NWC, wc = wid % NWC;
    const int row0 = blockIdx.y * 256;
    const int col0 = blockIdx.x * (64 * NWC);
    const u16* Bb = B + (size_t)(row0 >> bshift) * strideB;

    // staging per-thread constants (each call: 512 lanes x 16B = 8KB)
    int s_row[2], s_k[2], s_dst[2];
    #pragma unroll
    for (int c = 0; c < 2; ++c) {
        int p = c * 512 + tid;
        int line = p >> 3, ls = (p & 7) ^ (line & 7);
        s_row[c] = 2 * line + (ls >> 2);
        s_k[c]   = (ls & 3) * 8;
        s_dst[c] = (c * 512 + (tid & ~63)) * 8;
    }

    auto stageA = [&](int T) {
        const int sb = (T & 3) * SLOT, k0 = T * 32;
        #pragma unroll
        for (int c = 0; c < 2; ++c)
            g2lds16(A + (size_t)(row0 + s_row[c]) * lda + k0 + s_k[c],
                    &lds[sb + s_dst[c]]);
    };
    auto stageB = [&](int T) {
        const int sb = (T & 3) * SLOT, k0 = T * 32;
        #pragma unroll
        for (int c = 0; c < SBC; ++c)
            g2lds16(Bb + (size_t)(col0 + s_row[c]) * ldb + k0 + s_k[c],
                    &lds[sb + 8192 + s_dst[c]]);
    };

    const int rl = lane & 15, kq = lane >> 4;
    const int ls2  = ((rl & 1) * 4 + kq) ^ ((rl >> 1) & 7);
    const int aoff = (wr * (MACC * 8) + (rl >> 1)) * 64 + ls2 * 8;
    const int boff = 8192 + (wc * 32 + (rl >> 1)) * 64 + ls2 * 8;

    f32x4 acc[MACC][4] = {};
    bf16x8 afr[PH], bfr[4];

    stageA(0); stageB(0); stageA(1); stageB(1); stageA(2); stageB(2);
    waitcnt_vm<2 * L>();
    __builtin_amdgcn_s_barrier();

    const int NT = K >> 5;
    for (int T = 0; T < NT; ++T) {
        const int sb = (T & 3) * SLOT;

        // ---- phase 1 ----
        #pragma unroll
        for (int m = 0; m < PH; ++m) afr[m] = *(const bf16x8*)&lds[sb + aoff + m * 512];
        #pragma unroll
        for (int n = 0; n < 4; ++n)  bfr[n] = *(const bf16x8*)&lds[sb + boff + n * 512];
        if (T + 3 < NT) stageA(T + 3);
        __builtin_amdgcn_s_barrier();
        asm volatile("s_waitcnt lgkmcnt(0)" ::: "memory");
        __builtin_amdgcn_sched_barrier(0);
        __builtin_amdgcn_s_setprio(1);
        #pragma unroll
        for (int m = 0; m < PH; ++m)
            #pragma unroll
            for (int n = 0; n < 4; ++n)
                acc[m][n] = __builtin_amdgcn_mfma_f32_16x16x32_bf16(afr[m], bfr[n], acc[m][n], 0, 0, 0);
        __builtin_amdgcn_s_setprio(0);
        __builtin_amdgcn_s_barrier();

        // ---- phase 2 ----
        #pragma unroll
        for (int m = 0; m < PH; ++m) afr[m] = *(const bf16x8*)&lds[sb + aoff + (m + PH) * 512];
        if (T + 3 < NT) stageB(T + 3);
        if (T < NT - 3)       waitcnt_vm<2 * L>();
        else if (T == NT - 3) waitcnt_vm<L>();
        else if (T == NT - 2) waitcnt_vm<0>();
        __builtin_amdgcn_s_barrier();
        asm volatile("s_waitcnt lgkmcnt(0)" ::: "memory");
        __builtin_amdgcn_sched_barrier(0);
        __builtin_amdgcn_s_setprio(1);
        #pragma unroll
        for (int m = 0; m < PH; ++m)
            #pragma unroll
            for (int n = 0; n < 4; ++n)
                acc[m + PH][n] = __builtin_amdgcn_mfma_f32_16x16x32_bf16(afr[m], bfr[n], acc[m + PH][n], 0, 0, 0);
        __builtin_amdgcn_s_setprio(0);
        __builtin_amdgcn_s_barrier();
    }

    // ---------- epilogue ----------
    // C/D frag: col = col0 + wc*64 + n*16 + rl ; row = row0 + wr*MACC*16 + m*16 + kq*4 + j
    const int kq4 = kq * 4;

    if constexpr (MODE == 1) {
        float* C = (float*)Cv;
        #pragma unroll
        for (int m = 0; m < MACC; ++m)
            #pragma unroll
            for (int j = 0; j < 4; ++j) {
                size_t r = (size_t)(row0 + wr * (MACC * 16) + m * 16 + kq4 + j) * ldc;
                #pragma unroll
                for (int n = 0; n < 4; ++n)
                    C[r + col0 + wc * 64 + n * 16 + rl] = acc[m][n][j] * scale;
            }
    } else if constexpr (MODE == 0) {
        // bf16: stage per-wave 64x64 f32 tiles in own LDS region, store coalesced
        float* tw = (float*)&lds[(size_t)wid * 8192];   // [64 rows][64 cols] swizzled
        u16* Cq = (u16*)Cv;
        #pragma unroll
        for (int h = 0; h < MACC / 4; ++h) {
            #pragma unroll
            for (int mm = 0; mm < 4; ++mm)
                #pragma unroll
                for (int n = 0; n < 4; ++n)
                    #pragma unroll
                    for (int j = 0; j < 4; ++j) {
                        int rowl = mm * 16 + kq4 + j;
                        int c2 = (rl + n * 16) ^ ((((rowl) >> 2) & 3) << 4);
                        tw[rowl * 64 + c2] = acc[h * 4 + mm][n][j];
                    }
            #pragma unroll
            for (int it = 0; it < 16; ++it) {
                int rowr = it * 4 + kq;
                int c2 = (rl * 4) ^ ((it & 3) << 4);
                f32x4 v4 = *(const f32x4*)&tw[rowr * 64 + c2];
                ushort4 u{ f2bf(v4[0]), f2bf(v4[1]), f2bf(v4[2]), f2bf(v4[3]) };
                *(ushort4*)&Cq[(size_t)(row0 + wr * (MACC * 16) + h * 64 + rowr) * ldc
                               + col0 + wc * 64 + rl * 4] = u;
            }
        }
    } else {
        // MODE 3 (NWC=2): transposed bf16 store, wave tile 64(s) x 64(f) -> vT[f][s]
        u32* tv = (u32*)&lds[(size_t)wid * 4096];       // [64 f][32 s2] swizzled (8KB)
        const int s0  = row0 + wr * 64;
        const int f0v = col0 + wc * 64;
        #pragma unroll
        for (int m = 0; m < 4; ++m)
            #pragma unroll
            for (int n = 0; n < 4; ++n)
                #pragma unroll
                for (int j2 = 0; j2 < 2; ++j2) {
                    int fl = rl + n * 16;
                    int s2 = m * 8 + kq * 2 + j2;
                    u32 pk = (u32)f2bf(acc[m][n][j2 * 2])
                           | ((u32)f2bf(acc[m][n][j2 * 2 + 1]) << 16);
                    tv[fl * 32 + (s2 ^ ((fl & 7) << 2))] = pk;
                }
        #pragma unroll
        for (int it = 0; it < 8; ++it) {
            int fr = it * 8 + (lane >> 3);
            int ck = lane & 7;
            int s2s = (ck * 4) ^ ((fr & 7) << 2);
            u32x4 v4 = *(const u32x4*)&tv[fr * 32 + s2s];
            *(u32x4*)&vTp[(size_t)(f0v + fr) * 8192 + s0 + ck * 8] = v4;
        }
    }
}

// ---------- row softmax (2048 f32 -> 2048 bf16 in-place per row) ----------
// One block per row. Writes bf16 P over the FIRST 4KB of the row's own 8KB
// storage (same row only -> no cross-block hazard). P row stride = 4096 u16.

__global__ __launch_bounds__(256)
void softmax_bf16(float* __restrict__ scores) {
    const size_t row = blockIdx.x;
    float* rp = scores + row * 2048;
    const int tid = threadIdx.x;
    const int lane = tid & 63, wid = tid >> 6;

    float4 a = reinterpret_cast<const float4*>(rp)[tid * 2];
    float4 b = reinterpret_cast<const float4*>(rp)[tid * 2 + 1];
    float v[8] = { a.x, a.y, a.z, a.w, b.x, b.y, b.z, b.w };

    float mx = v[0];
    #pragma unroll
    for (int j = 1; j < 8; ++j) mx = fmaxf(mx, v[j]);
    #pragma unroll
    for (int off = 32; off >= 1; off >>= 1) mx = fmaxf(mx, __shfl_xor(mx, off));

    __shared__ float red_mx[4], red_s[4];
    if (lane == 0) red_mx[wid] = mx;
    __syncthreads();
    mx = fmaxf(fmaxf(red_mx[0], red_mx[1]), fmaxf(red_mx[2], red_mx[3]));

    float s = 0.f;
    #pragma unroll
    for (int j = 0; j < 8; ++j) { v[j] = __expf(v[j] - mx); s += v[j]; }
    #pragma unroll
    for (int off = 32; off >= 1; off >>= 1) s += __shfl_xor(s, off);
    if (lane == 0) red_s[wid] = s;
    __syncthreads();
    s = (red_s[0] + red_s[1]) + (red_s[2] + red_s[3]);
    float inv = 1.0f / s;

    u16* pw = (u16*)rp;
    ushort4 u0{ f2bf(v[0] * inv), f2bf(v[1] * inv), f2bf(v[2] * inv), f2bf(v[3] * inv) };
    ushort4 u1{ f2bf(v[4] * inv), f2bf(v[5] * inv), f2bf(v[6] * inv), f2bf(v[7] * inv) };
    reinterpret_cast<ushort4*>(pw)[tid * 2]     = u0;
    reinterpret_cast<ushort4*>(pw)[tid * 2 + 1] = u1;
}

// ---------- launch ----------

extern "C" void kernel_launch(void* const* d_in, const int* in_sizes, int n_in,
                              void* d_out, int out_size, void* d_ws, size_t ws_size,
                              hipStream_t stream) {
    const float* x  = (const float*)d_in[0];
    const float* Wq = (const float*)d_in[1];
    const float* Wk = (const float*)d_in[2];
    const float* Wv = (const float*)d_in[3];

    // ws (MiB) — r4 plan: [0,64) sc f32 | aliased: [0,16) xb, [16,22) Wqkv
    // (both dead before sc is written) | [64,96) qk bf16 [8192][2048] |
    // [96,112) vT bf16 [1024][8192]
    const size_t MiB = 1024 * 1024;
    if (ws_size < 112 * MiB) return;
    char* base = (char*)d_ws;
    float* sc   = (float*)base;
    u16*  xb    = (u16*)base;
    u16*  Wqkvb = (u16*)(base + 16 * MiB);
    u16*  qkb   = (u16*)(base + 64 * MiB);
    u16*  vT    = (u16*)(base + 96 * MiB);

    cvt_all<<<2816, 256, 0, stream>>>(x, Wq, Wk, Wv, xb, Wqkvb);

    // qk = x @ [Wq;Wk]^T : M=8192, N=2048, K=1024 -> bf16 qkb   (grid = 256)
    gemm256<0, 4><<<dim3(8, 32), 512, 0, stream>>>(xb, Wqkvb, qkb, nullptr,
        1024, 1024, 1024, 2048, 31, 0, 1.0f);

    // v = x @ Wv^T, stored transposed -> vT[f][s_global]        (grid = 256)
    gemm256<3, 2><<<dim3(8, 32), 512, 0, stream>>>(xb, Wqkvb + 2097152, nullptr, vT,
        1024, 1024, 1024, 8192, 31, 0, 1.0f);

    // scores = q @ k^T / 32 : M=8192, N=2048, K=1024 -> f32 sc  (grid = 256)
    gemm256<1, 4><<<dim3(8, 32), 512, 0, stream>>>(qkb, qkb + 1024, sc, nullptr,
        1024, 2048, 2048, 2048, 11, (size_t)2048 * 2048, 0.03125f);

    // softmax rows -> bf16 P in place (P lda = 4096 u16)
    softmax_bf16<<<8192, 256, 0, stream>>>(sc);

    // out = P @ vT^T : M=8192, N=1024(f), K=2048(s) -> f32 d_out (grid = 256)
    gemm256<1, 2><<<dim3(8, 32), 512, 0, stream>>>((const u16*)sc, vT, d_out, nullptr,
        2048, 4096, 8192, 1024, 11, 2048, 1.0f);
}

// Round 9
// 171.799 us; speedup vs baseline: 1.0841x; 1.0823x over previous
//
#include <hip/hip_runtime.h>
#include <stdint.h>

typedef unsigned short u16;
typedef uint32_t u32;
typedef __bf16 bf16x8 __attribute__((ext_vector_type(8)));
typedef float f32x4 __attribute__((ext_vector_type(4)));
typedef uint32_t u32x4 __attribute__((ext_vector_type(4)));

__device__ __forceinline__ u16 f2bf(float f) {
    union { float f; uint32_t u; } c; c.f = f;
    return (u16)((c.u + 0x7fffu + ((c.u >> 16) & 1u)) >> 16);  // RNE
}

__device__ __forceinline__ void g2lds16(const u16* g, u16* l) {
    __builtin_amdgcn_global_load_lds(
        (__attribute__((address_space(1))) void*)(void*)(g),
        (__attribute__((address_space(3))) void*)(l),
        16, 0, 0);
}

template <int N> __device__ __forceinline__ void waitcnt_vm() {
    if constexpr      (N == 8) asm volatile("s_waitcnt vmcnt(8)" ::: "memory");
    else if constexpr (N == 6) asm volatile("s_waitcnt vmcnt(6)" ::: "memory");
    else if constexpr (N == 4) asm volatile("s_waitcnt vmcnt(4)" ::: "memory");
    else if constexpr (N == 3) asm volatile("s_waitcnt vmcnt(3)" ::: "memory");
    else                       asm volatile("s_waitcnt vmcnt(0)" ::: "memory");
}

// ---------- fused f32 -> bf16 convert (x, Wq, Wk, Wv in one launch) ----------

__global__ __launch_bounds__(256)
void cvt_all(const float* __restrict__ x, const float* __restrict__ wq,
             const float* __restrict__ wk, const float* __restrict__ wv,
             u16* __restrict__ xb, u16* __restrict__ wb) {
    const int b = blockIdx.x, tid = threadIdx.x;
    const float* src; u16* dst; int off;
    if (b < 2048) { src = x; dst = xb; off = b * 1024; }
    else {
        int w = (b - 2048) >> 8;
        src = (w == 0) ? wq : (w == 1) ? wk : wv;
        dst = wb + (size_t)w * 1048576;
        off = ((b - 2048) & 255) * 1024;
    }
    #pragma unroll
    for (int k2 = 0; k2 < 4; ++k2) {
        int i = off + k2 * 256 + tid;
        float4 f = reinterpret_cast<const float4*>(src)[i];
        ushort4 u{ f2bf(f.x), f2bf(f.y), f2bf(f.z), f2bf(f.w) };
        reinterpret_cast<ushort4*>(dst)[i] = u;
    }
}

// ---------- 256xBN deep-pipelined B^T GEMM ----------
// C[m][n] = scale * sum_k A[m][k]*B[n][k].  BK=32, 4-slot LDS ring, 8 waves.
// NWC=4: BN=256, waves 2Mx4N (wave tile 128x64), 128KB LDS, L=4 loads/tile.
// NWC=2: BN=128, waves 4Mx2N (wave tile  64x64),  96KB LDS, L=3 loads/tile.
// MODE 0: bf16 row-major via LDS-staged coalesced store (NWC=4).
// MODE 1: f32*scale direct store.
// MODE 3: bf16 transposed store to vT[1024][8192] (NWC=2).
// T1: XCD-aware block swizzle — grid must be 8x32 (256 blocks, 32/XCD).

template <int MODE, int NWC>
__global__ __launch_bounds__(512, 2)
void gemm256(const u16* __restrict__ A, const u16* __restrict__ B,
             void* __restrict__ Cv, u16* __restrict__ vTp,
             int K, int lda, int ldb, int ldc,
             int bshift, size_t strideB, float scale)
{
    constexpr int MACC = (NWC == 4) ? 8 : 4;   // A-frag repeats per wave
    constexpr int PH   = MACC / 2;             // per phase
    constexpr int SLOT = 8192 + 2048 * NWC;    // u16 per ring slot
    constexpr int SBC  = NWC / 2;              // B stage calls per tile
    constexpr int L    = 2 + SBC;              // loads per tile

    __shared__ __align__(16) u16 lds[4 * SLOT];

    const int tid  = threadIdx.x;
    const int wid  = tid >> 6, lane = tid & 63;
    const int wr = wid / NWC, wc = wid % NWC;

    // T1 XCD swizzle: hardware XCD ~ lin%8; give each XCD a contiguous
    // 4-y-strip x 8-x region so A-panels/B-panels are L2-resident per XCD.
    const int lin  = blockIdx.y * gridDim.x + blockIdx.x;   // 0..255
    const int virt = (lin & 7) * 32 + (lin >> 3);
    const int bx = virt & 7, by = virt >> 3;
    const int row0 = by * 256;
    const int col0 = bx * (64 * NWC);
    const u16* Bb = B + (size_t)(row0 >> bshift) * strideB;

    // staging per-thread constants (each call: 512 lanes x 16B = 8KB)
    int s_row[2], s_k[2], s_dst[2];
    #pragma unroll
    for (int c = 0; c < 2; ++c) {
        int p = c * 512 + tid;
        int line = p >> 3, ls = (p & 7) ^ (line & 7);
        s_row[c] = 2 * line + (ls >> 2);
        s_k[c]   = (ls & 3) * 8;
        s_dst[c] = (c * 512 + (tid & ~63)) * 8;
    }

    auto stageA = [&](int T) {
        const int sb = (T & 3) * SLOT, k0 = T * 32;
        #pragma unroll
        for (int c = 0; c < 2; ++c)
            g2lds16(A + (size_t)(row0 + s_row[c]) * lda + k0 + s_k[c],
                    &lds[sb + s_dst[c]]);
    };
    auto stageB = [&](int T) {
        const int sb = (T & 3) * SLOT, k0 = T * 32;
        #pragma unroll
        for (int c = 0; c < SBC; ++c)
            g2lds16(Bb + (size_t)(col0 + s_row[c]) * ldb + k0 + s_k[c],
                    &lds[sb + 8192 + s_dst[c]]);
    };

    const int rl = lane & 15, kq = lane >> 4;
    const int ls2  = ((rl & 1) * 4 + kq) ^ ((rl >> 1) & 7);
    const int aoff = (wr * (MACC * 8) + (rl >> 1)) * 64 + ls2 * 8;
    const int boff = 8192 + (wc * 32 + (rl >> 1)) * 64 + ls2 * 8;

    f32x4 acc[MACC][4] = {};
    bf16x8 afr[PH], bfr[4];

    stageA(0); stageB(0); stageA(1); stageB(1); stageA(2); stageB(2);
    waitcnt_vm<2 * L>();
    __builtin_amdgcn_s_barrier();

    const int NT = K >> 5;
    for (int T = 0; T < NT; ++T) {
        const int sb = (T & 3) * SLOT;

        // ---- phase 1 ----
        #pragma unroll
        for (int m = 0; m < PH; ++m) afr[m] = *(const bf16x8*)&lds[sb + aoff + m * 512];
        #pragma unroll
        for (int n = 0; n < 4; ++n)  bfr[n] = *(const bf16x8*)&lds[sb + boff + n * 512];
        if (T + 3 < NT) stageA(T + 3);
        __builtin_amdgcn_s_barrier();
        asm volatile("s_waitcnt lgkmcnt(0)" ::: "memory");
        __builtin_amdgcn_sched_barrier(0);
        __builtin_amdgcn_s_setprio(1);
        #pragma unroll
        for (int m = 0; m < PH; ++m)
            #pragma unroll
            for (int n = 0; n < 4; ++n)
                acc[m][n] = __builtin_amdgcn_mfma_f32_16x16x32_bf16(afr[m], bfr[n], acc[m][n], 0, 0, 0);
        __builtin_amdgcn_s_setprio(0);
        __builtin_amdgcn_s_barrier();

        // ---- phase 2 ----
        #pragma unroll
        for (int m = 0; m < PH; ++m) afr[m] = *(const bf16x8*)&lds[sb + aoff + (m + PH) * 512];
        if (T + 3 < NT) stageB(T + 3);
        if (T < NT - 3)       waitcnt_vm<2 * L>();
        else if (T == NT - 3) waitcnt_vm<L>();
        else if (T == NT - 2) waitcnt_vm<0>();
        __builtin_amdgcn_s_barrier();
        asm volatile("s_waitcnt lgkmcnt(0)" ::: "memory");
        __builtin_amdgcn_sched_barrier(0);
        __builtin_amdgcn_s_setprio(1);
        #pragma unroll
        for (int m = 0; m < PH; ++m)
            #pragma unroll
            for (int n = 0; n < 4; ++n)
                acc[m + PH][n] = __builtin_amdgcn_mfma_f32_16x16x32_bf16(afr[m], bfr[n], acc[m + PH][n], 0, 0, 0);
        __builtin_amdgcn_s_setprio(0);
        __builtin_amdgcn_s_barrier();
    }

    // ---------- epilogue ----------
    // C/D frag: col = col0 + wc*64 + n*16 + rl ; row = row0 + wr*MACC*16 + m*16 + kq*4 + j
    const int kq4 = kq * 4;

    if constexpr (MODE == 1) {
        float* C = (float*)Cv;
        #pragma unroll
        for (int m = 0; m < MACC; ++m)
            #pragma unroll
            for (int j = 0; j < 4; ++j) {
                size_t r = (size_t)(row0 + wr * (MACC * 16) + m * 16 + kq4 + j) * ldc;
                #pragma unroll
                for (int n = 0; n < 4; ++n)
                    C[r + col0 + wc * 64 + n * 16 + rl] = acc[m][n][j] * scale;
            }
    } else if constexpr (MODE == 0) {
        // bf16: stage per-wave 64x64 f32 tiles in own LDS region, store coalesced
        float* tw = (float*)&lds[(size_t)wid * 8192];   // [64 rows][64 cols] swizzled
        u16* Cq = (u16*)Cv;
        #pragma unroll
        for (int h = 0; h < MACC / 4; ++h) {
            #pragma unroll
            for (int mm = 0; mm < 4; ++mm)
                #pragma unroll
                for (int n = 0; n < 4; ++n)
                    #pragma unroll
                    for (int j = 0; j < 4; ++j) {
                        int rowl = mm * 16 + kq4 + j;
                        int c2 = (rl + n * 16) ^ ((((rowl) >> 2) & 3) << 4);
                        tw[rowl * 64 + c2] = acc[h * 4 + mm][n][j];
                    }
            #pragma unroll
            for (int it = 0; it < 16; ++it) {
                int rowr = it * 4 + kq;
                int c2 = (rl * 4) ^ ((it & 3) << 4);
                f32x4 v4 = *(const f32x4*)&tw[rowr * 64 + c2];
                ushort4 u{ f2bf(v4[0]), f2bf(v4[1]), f2bf(v4[2]), f2bf(v4[3]) };
                *(ushort4*)&Cq[(size_t)(row0 + wr * (MACC * 16) + h * 64 + rowr) * ldc
                               + col0 + wc * 64 + rl * 4] = u;
            }
        }
    } else {
        // MODE 3 (NWC=2): transposed bf16 store, wave tile 64(s) x 64(f) -> vT[f][s]
        u32* tv = (u32*)&lds[(size_t)wid * 4096];       // [64 f][32 s2] swizzled (8KB)
        const int s0  = row0 + wr * 64;
        const int f0v = col0 + wc * 64;
        #pragma unroll
        for (int m = 0; m < 4; ++m)
            #pragma unroll
            for (int n = 0; n < 4; ++n)
                #pragma unroll
                for (int j2 = 0; j2 < 2; ++j2) {
                    int fl = rl + n * 16;
                    int s2 = m * 8 + kq * 2 + j2;
                    u32 pk = (u32)f2bf(acc[m][n][j2 * 2])
                           | ((u32)f2bf(acc[m][n][j2 * 2 + 1]) << 16);
                    tv[fl * 32 + (s2 ^ ((fl & 7) << 2))] = pk;
                }
        #pragma unroll
        for (int it = 0; it < 8; ++it) {
            int fr = it * 8 + (lane >> 3);
            int ck = lane & 7;
            int s2s = (ck * 4) ^ ((fr & 7) << 2);
            u32x4 v4 = *(const u32x4*)&tv[fr * 32 + s2s];
            *(u32x4*)&vTp[(size_t)(f0v + fr) * 8192 + s0 + ck * 8] = v4;
        }
    }
}

// ---------- row softmax (2048 f32 -> 2048 bf16 in-place per row) ----------
// One block per row. Writes bf16 P over the FIRST 4KB of the row's own 8KB
// storage (same row only -> no cross-block hazard). P row stride = 4096 u16.

__global__ __launch_bounds__(256)
void softmax_bf16(float* __restrict__ scores) {
    const size_t row = blockIdx.x;
    float* rp = scores + row * 2048;
    const int tid = threadIdx.x;
    const int lane = tid & 63, wid = tid >> 6;

    float4 a = reinterpret_cast<const float4*>(rp)[tid * 2];
    float4 b = reinterpret_cast<const float4*>(rp)[tid * 2 + 1];
    float v[8] = { a.x, a.y, a.z, a.w, b.x, b.y, b.z, b.w };

    float mx = v[0];
    #pragma unroll
    for (int j = 1; j < 8; ++j) mx = fmaxf(mx, v[j]);
    #pragma unroll
    for (int off = 32; off >= 1; off >>= 1) mx = fmaxf(mx, __shfl_xor(mx, off));

    __shared__ float red_mx[4], red_s[4];
    if (lane == 0) red_mx[wid] = mx;
    __syncthreads();
    mx = fmaxf(fmaxf(red_mx[0], red_mx[1]), fmaxf(red_mx[2], red_mx[3]));

    float s = 0.f;
    #pragma unroll
    for (int j = 0; j < 8; ++j) { v[j] = __expf(v[j] - mx); s += v[j]; }
    #pragma unroll
    for (int off = 32; off >= 1; off >>= 1) s += __shfl_xor(s, off);
    if (lane == 0) red_s[wid] = s;
    __syncthreads();
    s = (red_s[0] + red_s[1]) + (red_s[2] + red_s[3]);
    float inv = 1.0f / s;

    u16* pw = (u16*)rp;
    ushort4 u0{ f2bf(v[0] * inv), f2bf(v[1] * inv), f2bf(v[2] * inv), f2bf(v[3] * inv) };
    ushort4 u1{ f2bf(v[4] * inv), f2bf(v[5] * inv), f2bf(v[6] * inv), f2bf(v[7] * inv) };
    reinterpret_cast<ushort4*>(pw)[tid * 2]     = u0;
    reinterpret_cast<ushort4*>(pw)[tid * 2 + 1] = u1;
}

// ---------- launch ----------

extern "C" void kernel_launch(void* const* d_in, const int* in_sizes, int n_in,
                              void* d_out, int out_size, void* d_ws, size_t ws_size,
                              hipStream_t stream) {
    const float* x  = (const float*)d_in[0];
    const float* Wq = (const float*)d_in[1];
    const float* Wk = (const float*)d_in[2];
    const float* Wv = (const float*)d_in[3];

    // ws (MiB): [0,64) sc f32 | aliased: [0,16) xb, [16,22) Wqkv
    // (both dead before sc is written) | [64,96) qk bf16 [8192][2048] |
    // [96,112) vT bf16 [1024][8192]
    const size_t MiB = 1024 * 1024;
    if (ws_size < 112 * MiB) return;
    char* base = (char*)d_ws;
    float* sc   = (float*)base;
    u16*  xb    = (u16*)base;
    u16*  Wqkvb = (u16*)(base + 16 * MiB);
    u16*  qkb   = (u16*)(base + 64 * MiB);
    u16*  vT    = (u16*)(base + 96 * MiB);

    cvt_all<<<2816, 256, 0, stream>>>(x, Wq, Wk, Wv, xb, Wqkvb);

    // qk = x @ [Wq;Wk]^T : M=8192, N=2048, K=1024 -> bf16 qkb   (grid = 256)
    gemm256<0, 4><<<dim3(8, 32), 512, 0, stream>>>(xb, Wqkvb, qkb, nullptr,
        1024, 1024, 1024, 2048, 31, 0, 1.0f);

    // v = x @ Wv^T, stored transposed -> vT[f][s_global]        (grid = 256)
    gemm256<3, 2><<<dim3(8, 32), 512, 0, stream>>>(xb, Wqkvb + 2097152, nullptr, vT,
        1024, 1024, 1024, 8192, 31, 0, 1.0f);

    // scores = q @ k^T / 32 : M=8192, N=2048, K=1024 -> f32 sc  (grid = 256)
    gemm256<1, 4><<<dim3(8, 32), 512, 0, stream>>>(qkb, qkb + 1024, sc, nullptr,
        1024, 2048, 2048, 2048, 11, (size_t)2048 * 2048, 0.03125f);

    // softmax rows -> bf16 P in place (P lda = 4096 u16)
    softmax_bf16<<<8192, 256, 0, stream>>>(sc);

    // out = P @ vT^T : M=8192, N=1024(f), K=2048(s) -> f32 d_out (grid = 256)
    gemm256<1, 2><<<dim3(8, 32), 512, 0, stream>>>((const u16*)sc, vT, d_out, nullptr,
        2048, 4096, 8192, 1024, 11, 2048, 1.0f);
}